// Round 17
// baseline (186.519 us; speedup 1.0000x reference)
//
#include <hip/hip_runtime.h>
#include <hip/hip_bf16.h>
#include <math.h>

#define N_NODES 400000
#define N_EDGES 2400000
#define NPG 40
#define N_GRAPHS 10000
#define IN_F 30
#define H1 30
#define H2 10
#define OUTF 4
#define GPB 2
#define PAIRS (N_GRAPHS / GPB)      // 5000
#define ROWS (GPB * NPG)            // 80 dst rows per pair
#define CAPE 768                    // per-pair capacity (real ~480 + pads)
#define NC 79                       // coarse buckets
#define PPC 64                      // pairs per coarse bucket
#define NPC (PPC * ROWS)            // 5120 nodes per coarse bucket
#define SRC_PER_BUCK 5120
#define CCAP 45056                  // coarse capacity (real ~30.4k + pads ~10.2k + 27sigma)
#define P1B 1280                    // p1 blocks (~1875 edges each)
#define P1D 32                      // per-bucket LDS depth (mean fill 23.7)
#define P2BPB 8
#define HPARTS 8                    // p1_hist parts per bucket
#define SENT 0xFFFFFFFFu

// ---------------- P1: ONE pass, single accumulate + single drain ------------------------
// dst entry: (src<<13) | (lp<<7) | row ; src entry: raw src id. Full-line flushes.
__global__ __launch_bounds__(256) void p1_split2(const int4* __restrict__ src4,
                                                 const int4* __restrict__ dst4,
                                                 int* __restrict__ ccurD,
                                                 int* __restrict__ ccurS,
                                                 unsigned* __restrict__ coarseD,
                                                 unsigned* __restrict__ coarseS) {
    __shared__ unsigned bufD[NC][P1D];
    __shared__ unsigned bufS[NC][P1D];
    __shared__ int cntD[NC], cntS[NC];
    __shared__ int ftotD[NC], fnfD[NC], fbaseD[NC];
    __shared__ int ftotS[NC], fnfS[NC], fbaseS[NC];
    int t = threadIdx.x;
    for (int i = t; i < NC; i += 256) { cntD[i] = 0; cntS[i] = 0; }
    __syncthreads();
    const int n4 = N_EDGES / 4;
    const int per = (n4 + P1B - 1) / P1B;      // 469 int4s per block
    int lo = blockIdx.x * per;
    int hi = lo + per; if (hi > n4) hi = n4;
    for (int i = lo + t; i < hi; i += 256) {
        int4 d = dst4[i];
        int4 s = src4[i];
        #pragma unroll
        for (int k = 0; k < 4; k++) {
            int dd = (k==0)?d.x:(k==1)?d.y:(k==2)?d.z:d.w;
            int ss = (k==0)?s.x:(k==1)?s.y:(k==2)?s.z:s.w;
            int bu = dd / NPC;
            int rem = dd - bu * NPC;
            int lp = rem / ROWS;
            int row = rem - lp * ROWS;
            unsigned e = ((unsigned)ss << 13) | ((unsigned)lp << 7) | (unsigned)row;
            int pos = atomicAdd(&cntD[bu], 1);
            if (pos < P1D) bufD[bu][pos] = e;
            else {  // ~4% tail spill: single-word random write, bounded ~2MB total
                int b2 = atomicAdd(&ccurD[bu * 16], 1);
                if (b2 < CCAP) coarseD[bu * CCAP + b2] = e;
            }
            int bs = ss / SRC_PER_BUCK;
            int ps = atomicAdd(&cntS[bs], 1);
            if (ps < P1D) bufS[bs][ps] = (unsigned)ss;
            else {
                int b2 = atomicAdd(&ccurS[bs * 16], 1);
                if (b2 < CCAP) coarseS[bs * CCAP + b2] = (unsigned)ss;
            }
        }
    }
    __syncthreads();
    // single drain, sentinel-padded to full 16-entry lines
    if (t < NC) {
        int tot = min(cntD[t], P1D);
        int nf = (tot + 15) & ~15;
        ftotD[t] = tot; fnfD[t] = nf;
        fbaseD[t] = nf ? atomicAdd(&ccurD[t * 16], nf) : 0;
        tot = min(cntS[t], P1D);
        nf = (tot + 15) & ~15;
        ftotS[t] = tot; fnfS[t] = nf;
        fbaseS[t] = nf ? atomicAdd(&ccurS[t * 16], nf) : 0;
    }
    __syncthreads();
    {
        int w = t >> 6, lane = t & 63;
        for (int bu = w; bu < NC; bu += 4) {
            int nf = fnfD[bu], base = fbaseD[bu], tot = ftotD[bu];
            if (nf && base + nf <= CCAP)
                for (int j = lane; j < nf; j += 64)
                    coarseD[bu * CCAP + base + j] = (j < tot) ? bufD[bu][j] : SENT;
            nf = fnfS[bu]; base = fbaseS[bu]; tot = ftotS[bu];
            if (nf && base + nf <= CCAP)
                for (int j = lane; j < nf; j += 64)
                    coarseS[bu * CCAP + base + j] = (j < tot) ? bufS[bu][j] : SENT;
        }
    }
}

// ---------------- P1c: per-bucket LDS histogram -> coalesced deg_out merge --------------
__global__ __launch_bounds__(256) void p1_hist(const unsigned* __restrict__ coarseS,
                                               const int* __restrict__ ccurS,
                                               int* __restrict__ deg_out) {
    __shared__ int hist[SRC_PER_BUCK];
    int bu = blockIdx.x / HPARTS;
    int part = blockIdx.x % HPARTS;
    int t = threadIdx.x;
    for (int i = t; i < SRC_PER_BUCK; i += 256) hist[i] = 0;
    __syncthreads();
    int total = min(ccurS[bu * 16], CCAP);
    int slice = (total + HPARTS - 1) / HPARTS;
    int lo = part * slice;
    int hi = min(lo + slice, total);
    const unsigned* cb = coarseS + (size_t)bu * CCAP;
    int base = bu * SRC_PER_BUCK;
    for (int i = lo + t; i < hi; i += 256) {
        unsigned ssv = cb[i];
        if (ssv < (unsigned)N_NODES) atomicAdd(&hist[(int)ssv - base], 1);
    }
    __syncthreads();
    int lim = min(SRC_PER_BUCK, N_NODES - base);
    for (int i = t; i < lim; i += 256) {
        int v = hist[i];
        if (v) atomicAdd(&deg_out[base + i], v);
    }
}

// ---------------- P2: single accumulate + single drain into per-pair segments -----------
__global__ __launch_bounds__(256) void p2_split(const unsigned* __restrict__ coarse,
                                                const int* __restrict__ ccur,
                                                int* __restrict__ gcursor,
                                                unsigned* __restrict__ binned) {
    __shared__ unsigned buf[PPC][128];
    __shared__ int cnt[PPC];
    __shared__ int ftot[PPC], fnf[PPC], fbase[PPC];
    int bu = blockIdx.x >> 3;
    int b2 = blockIdx.x & 7;
    int t = threadIdx.x;
    for (int i = t; i < PPC; i += 256) cnt[i] = 0;
    __syncthreads();
    int total = min(ccur[bu * 16], CCAP);
    int slice = (total + P2BPB - 1) / P2BPB;
    int lo = b2 * slice;
    int hi = min(lo + slice, total);
    const unsigned* cb = coarse + (size_t)bu * CCAP;
    for (int idx = lo + t * 4; idx < hi; idx += 1024) {
        uint4 r = *reinterpret_cast<const uint4*>(&cb[idx]);
        #pragma unroll
        for (int j = 0; j < 4; j++) {
            if (idx + j >= hi) break;
            unsigned e = (j==0)?r.x:(j==1)?r.y:(j==2)?r.z:r.w;
            if ((e >> 13) >= (unsigned)N_NODES) continue;   // sentinel
            int lp = (int)((e >> 7) & 63u);
            int pos = atomicAdd(&cnt[lp], 1);
            if (pos < 128) buf[lp][pos] = e;
            else {  // statistically never (mean ~59, depth 128)
                int pr = bu * PPC + lp;
                int pp = atomicAdd(&gcursor[pr], 1);
                if (pp < CAPE) binned[pr * CAPE + pp] = ((e >> 13) << 7) | (e & 127u);
            }
        }
    }
    __syncthreads();
    if (t < PPC) {
        int tot = min(cnt[t], 128);
        int nf = (tot + 15) & ~15;
        ftot[t] = tot; fnf[t] = nf;
        fbase[t] = nf ? atomicAdd(&gcursor[bu * PPC + t], nf) : 0;
    }
    __syncthreads();
    {
        int w = t >> 6, lane = t & 63;
        for (int lp = w; lp < PPC; lp += 4) {
            int nf = fnf[lp], base = fbase[lp], tot = ftot[lp];
            int pr = bu * PPC + lp;
            if (nf && base + nf <= CAPE)
                for (int j = lane; j < nf; j += 64) {
                    unsigned v = (j < tot) ? (((buf[lp][j] >> 13) << 7) | (buf[lp][j] & 127u)) : SENT;
                    binned[pr * CAPE + base + j] = v;
                }
        }
    }
}

// ---------------- fnorm[n][f] = bf16(feat[n][f] * rsqrt(max(deg_out,1))), 32-padded ------
__global__ void fnorm_kernel(const float* __restrict__ feat, const int* __restrict__ deg_out,
                             ushort* __restrict__ fnorm) {
    int idx = blockIdx.x * blockDim.x + threadIdx.x;
    int n = idx >> 5;
    int f = idx & 31;
    if (n >= N_NODES) return;
    float ns = rsqrtf(fmaxf((float)deg_out[n], 1.0f));
    float v = (f < IN_F) ? feat[(size_t)n * IN_F + f] * ns : 0.f;
    __hip_bfloat16 bv = __float2bfloat16(v);
    fnorm[((size_t)n << 5) + f] = *reinterpret_cast<ushort*>(&bv);
}

// ---------------- agg: LDS counting sort (global-read) -> row-parallel register gather ---
__global__ __launch_bounds__(256) void agg_pool_mlp(
    const uint4* __restrict__ fnorm4, const int* __restrict__ gcursor,
    const unsigned* __restrict__ binned,
    const float* __restrict__ W, const float* __restrict__ b,
    const float* __restrict__ W2, const float* __restrict__ b2,
    const float* __restrict__ W3, const float* __restrict__ b3,
    float* __restrict__ out) {
    int blk = blockIdx.x;
    int t = threadIdx.x;
    int l = t & 3;
    int q = t >> 2;
    __shared__ unsigned sS[CAPE];
    __shared__ int cnt_n[128];
    __shared__ int start_n[128];
    __shared__ int cur_n[128];
    __shared__ int scan_s[128];
    __shared__ float sAcc[ROWS][33];
    __shared__ float sW[IN_F * H1];
    __shared__ float smax[8][32];
    __shared__ float pooled[32];
    __shared__ float z[H2];

    int cnt = gcursor[blk];
    if (cnt > CAPE) cnt = CAPE;
    const unsigned* bb = binned + (size_t)blk * CAPE;

    for (int i = t; i < 128; i += 256) cnt_n[i] = 0;
    for (int i = t; i < IN_F * H1; i += 256) sW[i] = W[i];
    __syncthreads();

    for (int i = t; i < cnt; i += 256) atomicAdd(&cnt_n[bb[i] & 127u], 1);
    __syncthreads();

    if (t < 128) scan_s[t] = cnt_n[t];
    __syncthreads();
    for (int o = 1; o < 128; o <<= 1) {
        int y = 0;
        if (t < 128 && t >= o) y = scan_s[t - o];
        __syncthreads();
        if (t < 128) scan_s[t] += y;
        __syncthreads();
    }
    if (t < 128) {
        int ex = scan_s[t] - cnt_n[t];
        start_n[t] = ex;
        cur_n[t] = ex;
    }
    __syncthreads();

    for (int i = t; i < cnt; i += 256) {
        unsigned e = bb[i];       // L2-hot second read
        int row = (int)(e & 127u);
        int pos = atomicAdd(&cur_n[row], 1);
        sS[pos] = e >> 7;
    }
    __syncthreads();

    for (int nn = q; nn < ROWS; nn += 64) {
        float a[8];
        #pragma unroll
        for (int j = 0; j < 8; j++) a[j] = 0.f;
        int st = start_n[nn];
        int dg = cnt_n[nn];
        for (int j = 0; j < dg; ++j) {
            unsigned id = sS[st + j];
            uint4 r = fnorm4[(size_t)id * 4 + l];
            const unsigned* w = reinterpret_cast<const unsigned*>(&r);
            #pragma unroll
            for (int k = 0; k < 4; k++) {
                a[2 * k]     += __uint_as_float(w[k] << 16);
                a[2 * k + 1] += __uint_as_float(w[k] & 0xffff0000u);
            }
        }
        #pragma unroll
        for (int j = 0; j < 8; j++) sAcc[nn][l * 8 + j] = a[j];
    }
    __syncthreads();

    int f = t & 31;
    int hw = t >> 5;
    #pragma unroll
    for (int gi = 0; gi < GPB; gi++) {
        float m = -INFINITY;
        for (int n = hw; n < NPG; n += 8) {
            int row = gi * NPG + n;
            float nd = rsqrtf(fmaxf((float)cnt_n[row], 1.0f));
            if (f < H1) {
                float s2 = 0.f;
                #pragma unroll
                for (int k = 0; k < IN_F; k++) s2 += sAcc[row][k] * sW[k * H1 + f];
                m = fmaxf(m, s2 * nd + b[f]);
            }
        }
        smax[hw][f] = m;
        __syncthreads();
        if (t < 32) {
            float mm = smax[0][t];
            #pragma unroll
            for (int k = 1; k < 8; k++) mm = fmaxf(mm, smax[k][t]);
            pooled[t] = mm;
        }
        __syncthreads();
        if (t < H2) {
            float s2 = b2[t];
            #pragma unroll
            for (int k = 0; k < H1; k++) s2 += pooled[k] * W2[k * H2 + t];
            z[t] = fmaxf(s2, 0.f);
        }
        __syncthreads();
        if (t < OUTF) {
            float s3 = b3[t];
            #pragma unroll
            for (int k = 0; k < H2; k++) s3 += z[k] * W3[k * OUTF + t];
            out[(GPB * blk + gi) * OUTF + t] = 1.f / (1.f + expf(-s3));
        }
        __syncthreads();
    }
}

extern "C" void kernel_launch(void* const* d_in, const int* in_sizes, int n_in,
                              void* d_out, int out_size, void* d_ws, size_t ws_size,
                              hipStream_t stream) {
    const float* feat = (const float*)d_in[0];
    const int*   src  = (const int*)d_in[1];
    const int*   dst  = (const int*)d_in[2];
    const float* W  = (const float*)d_in[5];
    const float* b  = (const float*)d_in[6];
    const float* W2 = (const float*)d_in[7];
    const float* b2 = (const float*)d_in[8];
    const float* W3 = (const float*)d_in[9];
    const float* b3 = (const float*)d_in[10];
    float* out = (float*)d_out;

    char* ws = (char*)d_ws;
    int* deg_out = (int*)ws;                           // 400000 (zeroed)
    int* gcursor = deg_out + N_NODES;                  // 5120   (zeroed)
    int* ccurD   = gcursor + 5120;                     // 1280   (zeroed)
    int* ccurS   = ccurD + 1280;                       // 1280   (zeroed)
    unsigned* coarseD = (unsigned*)(ccurS + 1280);     // 79*45056
    unsigned* coarseS = coarseD + (size_t)NC * CCAP;   // 79*45056
    unsigned* binned  = coarseS + (size_t)NC * CCAP;   // 5000*768
    ushort* fnorm = (ushort*)(binned + (size_t)PAIRS * CAPE);  // 25.6MB

    hipMemsetAsync(deg_out, 0, sizeof(int) * (N_NODES + 5120 + 1280 + 1280), stream);

    p1_split2<<<P1B, 256, 0, stream>>>((const int4*)src, (const int4*)dst,
                                       ccurD, ccurS, coarseD, coarseS);
    p1_hist<<<NC * HPARTS, 256, 0, stream>>>(coarseS, ccurS, deg_out);

    p2_split<<<NC * P2BPB, 256, 0, stream>>>(coarseD, ccurD, gcursor, binned);

    fnorm_kernel<<<(N_NODES * 32 + 255) / 256, 256, 0, stream>>>(feat, deg_out, fnorm);

    agg_pool_mlp<<<PAIRS, 256, 0, stream>>>((const uint4*)fnorm, gcursor, binned,
                                            W, b, W2, b2, W3, b3, out);
}

// Round 18
// 169.366 us; speedup vs baseline: 1.1013x; 1.1013x over previous
//
#include <hip/hip_runtime.h>
#include <hip/hip_bf16.h>
#include <math.h>

#define N_NODES 400000
#define N_EDGES 2400000
#define NPG 40
#define N_GRAPHS 10000
#define IN_F 30
#define H1 30
#define H2 10
#define OUTF 4
#define GPB 2
#define PAIRS (N_GRAPHS / GPB)      // 5000
#define ROWS (GPB * NPG)            // 80 dst rows per pair
#define CAPE 768                    // per-pair capacity (real ~480 + pads)
#define NC 79                       // coarse buckets
#define PPC 64                      // pairs per coarse bucket
#define NPC (PPC * ROWS)            // 5120 nodes per coarse bucket
#define SRC_PER_BUCK 5120
#define CCAP 40960                  // coarse capacity (real ~30.4k + pads ~5.1k)
#define P1B 640                     // single-pass p1 blocks (~3752 edges each)
#define P1D 64                      // per-bucket LDS depth (mean fill 47.5)
#define P2BPB 8
#define HPARTS 8
#define SENT 0xFFFFFFFFu

// ---------------- P1: ONE pass, single accumulate + single drain ------------------------
// dst entry: (src<<13) | (lp<<7) | row ; src entry: raw src id. Full-line flushes.
__global__ __launch_bounds__(256) void p1_split2(const int4* __restrict__ src4,
                                                 const int4* __restrict__ dst4,
                                                 int* __restrict__ ccurD,
                                                 int* __restrict__ ccurS,
                                                 unsigned* __restrict__ coarseD,
                                                 unsigned* __restrict__ coarseS) {
    __shared__ unsigned bufD[NC][P1D];
    __shared__ unsigned bufS[NC][P1D];
    __shared__ int cntD[NC], cntS[NC];
    __shared__ int ftotD[NC], fnfD[NC], fbaseD[NC];
    __shared__ int ftotS[NC], fnfS[NC], fbaseS[NC];
    int t = threadIdx.x;
    for (int i = t; i < NC; i += 256) { cntD[i] = 0; cntS[i] = 0; }
    __syncthreads();
    const int n4 = N_EDGES / 4;
    const int per = (n4 + P1B - 1) / P1B;      // 938 int4s per block
    int lo = blockIdx.x * per;
    int hi = lo + per; if (hi > n4) hi = n4;
    for (int i = lo + t; i < hi; i += 256) {
        int4 d = dst4[i];
        int4 s = src4[i];
        #pragma unroll
        for (int k = 0; k < 4; k++) {
            int dd = (k==0)?d.x:(k==1)?d.y:(k==2)?d.z:d.w;
            int ss = (k==0)?s.x:(k==1)?s.y:(k==2)?s.z:s.w;
            int bu = dd / NPC;
            int rem = dd - bu * NPC;
            int lp = rem / ROWS;
            int row = rem - lp * ROWS;
            unsigned e = ((unsigned)ss << 13) | ((unsigned)lp << 7) | (unsigned)row;
            int pos = atomicAdd(&cntD[bu], 1);
            if (pos < P1D) bufD[bu][pos] = e;
            else {  // rare spill (E ~ 0.06/bucket/block)
                int b2 = atomicAdd(&ccurD[bu * 16], 1);
                if (b2 < CCAP) coarseD[bu * CCAP + b2] = e;
            }
            int bs = ss / SRC_PER_BUCK;
            int ps = atomicAdd(&cntS[bs], 1);
            if (ps < P1D) bufS[bs][ps] = (unsigned)ss;
            else {
                int b2 = atomicAdd(&ccurS[bs * 16], 1);
                if (b2 < CCAP) coarseS[bs * CCAP + b2] = (unsigned)ss;
            }
        }
    }
    __syncthreads();
    // single drain, sentinel-padded to full 16-entry lines
    if (t < NC) {
        int tot = min(cntD[t], P1D);
        int nf = (tot + 15) & ~15;
        ftotD[t] = tot; fnfD[t] = nf;
        fbaseD[t] = nf ? atomicAdd(&ccurD[t * 16], nf) : 0;
        tot = min(cntS[t], P1D);
        nf = (tot + 15) & ~15;
        ftotS[t] = tot; fnfS[t] = nf;
        fbaseS[t] = nf ? atomicAdd(&ccurS[t * 16], nf) : 0;
    }
    __syncthreads();
    {
        int w = t >> 6, lane = t & 63;
        for (int bu = w; bu < NC; bu += 4) {
            int nf = fnfD[bu], base = fbaseD[bu], tot = ftotD[bu];
            if (nf && base + nf <= CCAP)
                for (int j = lane; j < nf; j += 64)
                    coarseD[bu * CCAP + base + j] = (j < tot) ? bufD[bu][j] : SENT;
            nf = fnfS[bu]; base = fbaseS[bu]; tot = ftotS[bu];
            if (nf && base + nf <= CCAP)
                for (int j = lane; j < nf; j += 64)
                    coarseS[bu * CCAP + base + j] = (j < tot) ? bufS[bu][j] : SENT;
        }
    }
}

// ---------------- P1c: per-bucket LDS histogram -> coalesced deg_out merge --------------
__global__ __launch_bounds__(256) void p1_hist(const unsigned* __restrict__ coarseS,
                                               const int* __restrict__ ccurS,
                                               int* __restrict__ deg_out) {
    __shared__ int hist[SRC_PER_BUCK];
    int bu = blockIdx.x / HPARTS;
    int part = blockIdx.x % HPARTS;
    int t = threadIdx.x;
    for (int i = t; i < SRC_PER_BUCK; i += 256) hist[i] = 0;
    __syncthreads();
    int total = min(ccurS[bu * 16], CCAP);
    int slice = (total + HPARTS - 1) / HPARTS;
    int lo = part * slice;
    int hi = min(lo + slice, total);
    const unsigned* cb = coarseS + (size_t)bu * CCAP;
    int base = bu * SRC_PER_BUCK;
    for (int i = lo + t; i < hi; i += 256) {
        unsigned ssv = cb[i];
        if (ssv < (unsigned)N_NODES) atomicAdd(&hist[(int)ssv - base], 1);
    }
    __syncthreads();
    int lim = min(SRC_PER_BUCK, N_NODES - base);
    for (int i = t; i < lim; i += 256) {
        int v = hist[i];
        if (v) atomicAdd(&deg_out[base + i], v);
    }
}

// ---------------- P2: single accumulate + single drain into per-pair segments -----------
__global__ __launch_bounds__(256) void p2_split(const unsigned* __restrict__ coarse,
                                                const int* __restrict__ ccur,
                                                int* __restrict__ gcursor,
                                                unsigned* __restrict__ binned) {
    __shared__ unsigned buf[PPC][128];
    __shared__ int cnt[PPC];
    __shared__ int ftot[PPC], fnf[PPC], fbase[PPC];
    int bu = blockIdx.x >> 3;
    int b2 = blockIdx.x & 7;
    int t = threadIdx.x;
    for (int i = t; i < PPC; i += 256) cnt[i] = 0;
    __syncthreads();
    int total = min(ccur[bu * 16], CCAP);
    int slice = (total + P2BPB - 1) / P2BPB;
    int lo = b2 * slice;
    int hi = min(lo + slice, total);
    const unsigned* cb = coarse + (size_t)bu * CCAP;
    for (int idx = lo + t * 4; idx < hi; idx += 1024) {
        uint4 r = *reinterpret_cast<const uint4*>(&cb[idx]);
        #pragma unroll
        for (int j = 0; j < 4; j++) {
            if (idx + j >= hi) break;
            unsigned e = (j==0)?r.x:(j==1)?r.y:(j==2)?r.z:r.w;
            if ((e >> 13) >= (unsigned)N_NODES) continue;   // sentinel
            int lp = (int)((e >> 7) & 63u);
            int pos = atomicAdd(&cnt[lp], 1);
            if (pos < 128) buf[lp][pos] = e;
            else {  // statistically never (mean ~59, depth 128)
                int pr = bu * PPC + lp;
                int pp = atomicAdd(&gcursor[pr], 1);
                if (pp < CAPE) binned[pr * CAPE + pp] = ((e >> 13) << 7) | (e & 127u);
            }
        }
    }
    __syncthreads();
    if (t < PPC) {
        int tot = min(cnt[t], 128);
        int nf = (tot + 15) & ~15;
        ftot[t] = tot; fnf[t] = nf;
        fbase[t] = nf ? atomicAdd(&gcursor[bu * PPC + t], nf) : 0;
    }
    __syncthreads();
    {
        int w = t >> 6, lane = t & 63;
        for (int lp = w; lp < PPC; lp += 4) {
            int nf = fnf[lp], base = fbase[lp], tot = ftot[lp];
            int pr = bu * PPC + lp;
            if (nf && base + nf <= CAPE)
                for (int j = lane; j < nf; j += 64) {
                    unsigned v = (j < tot) ? (((buf[lp][j] >> 13) << 7) | (buf[lp][j] & 127u)) : SENT;
                    binned[pr * CAPE + base + j] = v;
                }
        }
    }
}

// ---------------- fnorm[n][f] = bf16(feat[n][f] * rsqrt(max(deg_out,1))), 32-padded ------
__global__ void fnorm_kernel(const float* __restrict__ feat, const int* __restrict__ deg_out,
                             ushort* __restrict__ fnorm) {
    int idx = blockIdx.x * blockDim.x + threadIdx.x;
    int n = idx >> 5;
    int f = idx & 31;
    if (n >= N_NODES) return;
    float ns = rsqrtf(fmaxf((float)deg_out[n], 1.0f));
    float v = (f < IN_F) ? feat[(size_t)n * IN_F + f] * ns : 0.f;
    __hip_bfloat16 bv = __float2bfloat16(v);
    fnorm[((size_t)n << 5) + f] = *reinterpret_cast<ushort*>(&bv);
}

// ---------------- agg: LDS counting sort (global-read) -> row-parallel register gather ---
__global__ __launch_bounds__(256) void agg_pool_mlp(
    const uint4* __restrict__ fnorm4, const int* __restrict__ gcursor,
    const unsigned* __restrict__ binned,
    const float* __restrict__ W, const float* __restrict__ b,
    const float* __restrict__ W2, const float* __restrict__ b2,
    const float* __restrict__ W3, const float* __restrict__ b3,
    float* __restrict__ out) {
    int blk = blockIdx.x;
    int t = threadIdx.x;
    int l = t & 3;
    int q = t >> 2;
    __shared__ unsigned sS[CAPE];
    __shared__ int cnt_n[128];
    __shared__ int start_n[128];
    __shared__ int cur_n[128];
    __shared__ int scan_s[128];
    __shared__ float sAcc[ROWS][33];
    __shared__ float sW[IN_F * H1];
    __shared__ float smax[8][32];
    __shared__ float pooled[32];
    __shared__ float z[H2];

    int cnt = gcursor[blk];
    if (cnt > CAPE) cnt = CAPE;
    const unsigned* bb = binned + (size_t)blk * CAPE;

    for (int i = t; i < 128; i += 256) cnt_n[i] = 0;
    for (int i = t; i < IN_F * H1; i += 256) sW[i] = W[i];
    __syncthreads();

    for (int i = t; i < cnt; i += 256) atomicAdd(&cnt_n[bb[i] & 127u], 1);
    __syncthreads();

    if (t < 128) scan_s[t] = cnt_n[t];
    __syncthreads();
    for (int o = 1; o < 128; o <<= 1) {
        int y = 0;
        if (t < 128 && t >= o) y = scan_s[t - o];
        __syncthreads();
        if (t < 128) scan_s[t] += y;
        __syncthreads();
    }
    if (t < 128) {
        int ex = scan_s[t] - cnt_n[t];
        start_n[t] = ex;
        cur_n[t] = ex;
    }
    __syncthreads();

    for (int i = t; i < cnt; i += 256) {
        unsigned e = bb[i];       // L2-hot second read
        int row = (int)(e & 127u);
        int pos = atomicAdd(&cur_n[row], 1);
        sS[pos] = e >> 7;
    }
    __syncthreads();

    for (int nn = q; nn < ROWS; nn += 64) {
        float a[8];
        #pragma unroll
        for (int j = 0; j < 8; j++) a[j] = 0.f;
        int st = start_n[nn];
        int dg = cnt_n[nn];
        for (int j = 0; j < dg; ++j) {
            unsigned id = sS[st + j];
            uint4 r = fnorm4[(size_t)id * 4 + l];
            const unsigned* w = reinterpret_cast<const unsigned*>(&r);
            #pragma unroll
            for (int k = 0; k < 4; k++) {
                a[2 * k]     += __uint_as_float(w[k] << 16);
                a[2 * k + 1] += __uint_as_float(w[k] & 0xffff0000u);
            }
        }
        #pragma unroll
        for (int j = 0; j < 8; j++) sAcc[nn][l * 8 + j] = a[j];
    }
    __syncthreads();

    int f = t & 31;
    int hw = t >> 5;
    #pragma unroll
    for (int gi = 0; gi < GPB; gi++) {
        float m = -INFINITY;
        for (int n = hw; n < NPG; n += 8) {
            int row = gi * NPG + n;
            float nd = rsqrtf(fmaxf((float)cnt_n[row], 1.0f));
            if (f < H1) {
                float s2 = 0.f;
                #pragma unroll
                for (int k = 0; k < IN_F; k++) s2 += sAcc[row][k] * sW[k * H1 + f];
                m = fmaxf(m, s2 * nd + b[f]);
            }
        }
        smax[hw][f] = m;
        __syncthreads();
        if (t < 32) {
            float mm = smax[0][t];
            #pragma unroll
            for (int k = 1; k < 8; k++) mm = fmaxf(mm, smax[k][t]);
            pooled[t] = mm;
        }
        __syncthreads();
        if (t < H2) {
            float s2 = b2[t];
            #pragma unroll
            for (int k = 0; k < H1; k++) s2 += pooled[k] * W2[k * H2 + t];
            z[t] = fmaxf(s2, 0.f);
        }
        __syncthreads();
        if (t < OUTF) {
            float s3 = b3[t];
            #pragma unroll
            for (int k = 0; k < H2; k++) s3 += z[k] * W3[k * OUTF + t];
            out[(GPB * blk + gi) * OUTF + t] = 1.f / (1.f + expf(-s3));
        }
        __syncthreads();
    }
}

extern "C" void kernel_launch(void* const* d_in, const int* in_sizes, int n_in,
                              void* d_out, int out_size, void* d_ws, size_t ws_size,
                              hipStream_t stream) {
    const float* feat = (const float*)d_in[0];
    const int*   src  = (const int*)d_in[1];
    const int*   dst  = (const int*)d_in[2];
    const float* W  = (const float*)d_in[5];
    const float* b  = (const float*)d_in[6];
    const float* W2 = (const float*)d_in[7];
    const float* b2 = (const float*)d_in[8];
    const float* W3 = (const float*)d_in[9];
    const float* b3 = (const float*)d_in[10];
    float* out = (float*)d_out;

    char* ws = (char*)d_ws;
    int* deg_out = (int*)ws;                           // 400000 (zeroed)
    int* gcursor = deg_out + N_NODES;                  // 5120   (zeroed)
    int* ccurD   = gcursor + 5120;                     // 1280   (zeroed)
    int* ccurS   = ccurD + 1280;                       // 1280   (zeroed)
    unsigned* coarseD = (unsigned*)(ccurS + 1280);     // 79*40960
    unsigned* coarseS = coarseD + (size_t)NC * CCAP;   // 79*40960
    unsigned* binned  = coarseS + (size_t)NC * CCAP;   // 5000*768
    ushort* fnorm = (ushort*)(binned + (size_t)PAIRS * CAPE);  // 25.6MB

    hipMemsetAsync(deg_out, 0, sizeof(int) * (N_NODES + 5120 + 1280 + 1280), stream);

    p1_split2<<<P1B, 256, 0, stream>>>((const int4*)src, (const int4*)dst,
                                       ccurD, ccurS, coarseD, coarseS);
    p1_hist<<<NC * HPARTS, 256, 0, stream>>>(coarseS, ccurS, deg_out);

    p2_split<<<NC * P2BPB, 256, 0, stream>>>(coarseD, ccurD, gcursor, binned);

    fnorm_kernel<<<(N_NODES * 32 + 255) / 256, 256, 0, stream>>>(feat, deg_out, fnorm);

    agg_pool_mlp<<<PAIRS, 256, 0, stream>>>((const uint4*)fnorm, gcursor, binned,
                                            W, b, W2, b2, W3, b3, out);
}

// Round 19
// 161.964 us; speedup vs baseline: 1.1516x; 1.0457x over previous
//
#include <hip/hip_runtime.h>
#include <hip/hip_bf16.h>
#include <math.h>

#define N_NODES 400000
#define N_EDGES 2400000
#define NPG 40
#define N_GRAPHS 10000
#define IN_F 30
#define H1 30
#define H2 10
#define OUTF 4
#define GPB 2
#define PAIRS (N_GRAPHS / GPB)      // 5000
#define ROWS (GPB * NPG)            // 80 dst rows per pair
#define CAPE 768                    // per-pair capacity (real ~480 + pads)
#define NC 79                       // coarse buckets
#define PPC 64                      // pairs per coarse bucket
#define NPC (PPC * ROWS)            // 5120 nodes per coarse bucket
#define SRC_PER_BUCK 5120
#define CCAP 40960                  // coarse capacity (real ~30.4k + pads ~5.1k)
#define P1B 640                     // single-pass p1 blocks (~3752 edges each)
#define P1D 64                      // per-bucket LDS depth (mean fill 47.5)
#define P1T 512                     // p1 threads (8 waves -> 24 waves/CU at 3 blocks)
#define P2BPB 8
#define P2T 512                     // p2 threads
#define HPARTS 8
#define SENT 0xFFFFFFFFu

// ---------------- P1: ONE pass, single accumulate + single drain (512 thr) --------------
// dst entry: (src<<13) | (lp<<7) | row ; src entry: raw src id. Full-line flushes.
__global__ __launch_bounds__(P1T) void p1_split2(const int4* __restrict__ src4,
                                                 const int4* __restrict__ dst4,
                                                 int* __restrict__ ccurD,
                                                 int* __restrict__ ccurS,
                                                 unsigned* __restrict__ coarseD,
                                                 unsigned* __restrict__ coarseS) {
    __shared__ unsigned bufD[NC][P1D];
    __shared__ unsigned bufS[NC][P1D];
    __shared__ int cntD[NC], cntS[NC];
    __shared__ int ftotD[NC], fnfD[NC], fbaseD[NC];
    __shared__ int ftotS[NC], fnfS[NC], fbaseS[NC];
    int t = threadIdx.x;
    for (int i = t; i < NC; i += P1T) { cntD[i] = 0; cntS[i] = 0; }
    __syncthreads();
    const int n4 = N_EDGES / 4;
    const int per = (n4 + P1B - 1) / P1B;      // 938 int4s per block
    int lo = blockIdx.x * per;
    int hi = lo + per; if (hi > n4) hi = n4;
    for (int i = lo + t; i < hi; i += P1T) {
        int4 d = dst4[i];
        int4 s = src4[i];
        #pragma unroll
        for (int k = 0; k < 4; k++) {
            int dd = (k==0)?d.x:(k==1)?d.y:(k==2)?d.z:d.w;
            int ss = (k==0)?s.x:(k==1)?s.y:(k==2)?s.z:s.w;
            int bu = dd / NPC;
            int rem = dd - bu * NPC;
            int lp = rem / ROWS;
            int row = rem - lp * ROWS;
            unsigned e = ((unsigned)ss << 13) | ((unsigned)lp << 7) | (unsigned)row;
            int pos = atomicAdd(&cntD[bu], 1);
            if (pos < P1D) bufD[bu][pos] = e;
            else {  // rare spill
                int b2 = atomicAdd(&ccurD[bu * 16], 1);
                if (b2 < CCAP) coarseD[bu * CCAP + b2] = e;
            }
            int bs = ss / SRC_PER_BUCK;
            int ps = atomicAdd(&cntS[bs], 1);
            if (ps < P1D) bufS[bs][ps] = (unsigned)ss;
            else {
                int b2 = atomicAdd(&ccurS[bs * 16], 1);
                if (b2 < CCAP) coarseS[bs * CCAP + b2] = (unsigned)ss;
            }
        }
    }
    __syncthreads();
    // single drain, sentinel-padded to full 16-entry lines
    if (t < NC) {
        int tot = min(cntD[t], P1D);
        int nf = (tot + 15) & ~15;
        ftotD[t] = tot; fnfD[t] = nf;
        fbaseD[t] = nf ? atomicAdd(&ccurD[t * 16], nf) : 0;
        tot = min(cntS[t], P1D);
        nf = (tot + 15) & ~15;
        ftotS[t] = tot; fnfS[t] = nf;
        fbaseS[t] = nf ? atomicAdd(&ccurS[t * 16], nf) : 0;
    }
    __syncthreads();
    {
        int w = t >> 6, lane = t & 63;      // 8 waves
        for (int bu = w; bu < NC; bu += 8) {
            int nf = fnfD[bu], base = fbaseD[bu], tot = ftotD[bu];
            if (nf && base + nf <= CCAP)
                for (int j = lane; j < nf; j += 64)
                    coarseD[bu * CCAP + base + j] = (j < tot) ? bufD[bu][j] : SENT;
            nf = fnfS[bu]; base = fbaseS[bu]; tot = ftotS[bu];
            if (nf && base + nf <= CCAP)
                for (int j = lane; j < nf; j += 64)
                    coarseS[bu * CCAP + base + j] = (j < tot) ? bufS[bu][j] : SENT;
        }
    }
}

// ---------------- P1c: per-bucket LDS histogram -> coalesced deg_out merge --------------
__global__ __launch_bounds__(256) void p1_hist(const unsigned* __restrict__ coarseS,
                                               const int* __restrict__ ccurS,
                                               int* __restrict__ deg_out) {
    __shared__ int hist[SRC_PER_BUCK];
    int bu = blockIdx.x / HPARTS;
    int part = blockIdx.x % HPARTS;
    int t = threadIdx.x;
    for (int i = t; i < SRC_PER_BUCK; i += 256) hist[i] = 0;
    __syncthreads();
    int total = min(ccurS[bu * 16], CCAP);
    int slice = (total + HPARTS - 1) / HPARTS;
    int lo = part * slice;
    int hi = min(lo + slice, total);
    const unsigned* cb = coarseS + (size_t)bu * CCAP;
    int base = bu * SRC_PER_BUCK;
    for (int i = lo + t; i < hi; i += 256) {
        unsigned ssv = cb[i];
        if (ssv < (unsigned)N_NODES) atomicAdd(&hist[(int)ssv - base], 1);
    }
    __syncthreads();
    int lim = min(SRC_PER_BUCK, N_NODES - base);
    for (int i = t; i < lim; i += 256) {
        int v = hist[i];
        if (v) atomicAdd(&deg_out[base + i], v);
    }
}

// ---------------- P2: single accumulate + single drain (512 thr) ------------------------
__global__ __launch_bounds__(P2T) void p2_split(const unsigned* __restrict__ coarse,
                                                const int* __restrict__ ccur,
                                                int* __restrict__ gcursor,
                                                unsigned* __restrict__ binned) {
    __shared__ unsigned buf[PPC][128];
    __shared__ int cnt[PPC];
    __shared__ int ftot[PPC], fnf[PPC], fbase[PPC];
    int bu = blockIdx.x >> 3;
    int b2 = blockIdx.x & 7;
    int t = threadIdx.x;
    for (int i = t; i < PPC; i += P2T) cnt[i] = 0;
    __syncthreads();
    int total = min(ccur[bu * 16], CCAP);
    int slice = (total + P2BPB - 1) / P2BPB;
    int lo = b2 * slice;
    int hi = min(lo + slice, total);
    const unsigned* cb = coarse + (size_t)bu * CCAP;
    for (int idx = lo + t * 4; idx < hi; idx += P2T * 4) {
        uint4 r = *reinterpret_cast<const uint4*>(&cb[idx]);
        #pragma unroll
        for (int j = 0; j < 4; j++) {
            if (idx + j >= hi) break;
            unsigned e = (j==0)?r.x:(j==1)?r.y:(j==2)?r.z:r.w;
            if ((e >> 13) >= (unsigned)N_NODES) continue;   // sentinel
            int lp = (int)((e >> 7) & 63u);
            int pos = atomicAdd(&cnt[lp], 1);
            if (pos < 128) buf[lp][pos] = e;
            else {  // statistically never
                int pr = bu * PPC + lp;
                int pp = atomicAdd(&gcursor[pr], 1);
                if (pp < CAPE) binned[pr * CAPE + pp] = ((e >> 13) << 7) | (e & 127u);
            }
        }
    }
    __syncthreads();
    if (t < PPC) {
        int tot = min(cnt[t], 128);
        int nf = (tot + 15) & ~15;
        ftot[t] = tot; fnf[t] = nf;
        fbase[t] = nf ? atomicAdd(&gcursor[bu * PPC + t], nf) : 0;
    }
    __syncthreads();
    {
        int w = t >> 6, lane = t & 63;      // 8 waves
        for (int lp = w; lp < PPC; lp += 8) {
            int nf = fnf[lp], base = fbase[lp], tot = ftot[lp];
            int pr = bu * PPC + lp;
            if (nf && base + nf <= CAPE)
                for (int j = lane; j < nf; j += 64) {
                    unsigned v = (j < tot) ? (((buf[lp][j] >> 13) << 7) | (buf[lp][j] & 127u)) : SENT;
                    binned[pr * CAPE + base + j] = v;
                }
        }
    }
}

// ---------------- fnorm[n][f] = bf16(feat[n][f] * rsqrt(max(deg_out,1))), 32-padded ------
__global__ void fnorm_kernel(const float* __restrict__ feat, const int* __restrict__ deg_out,
                             ushort* __restrict__ fnorm) {
    int idx = blockIdx.x * blockDim.x + threadIdx.x;
    int n = idx >> 5;
    int f = idx & 31;
    if (n >= N_NODES) return;
    float ns = rsqrtf(fmaxf((float)deg_out[n], 1.0f));
    float v = (f < IN_F) ? feat[(size_t)n * IN_F + f] * ns : 0.f;
    __hip_bfloat16 bv = __float2bfloat16(v);
    fnorm[((size_t)n << 5) + f] = *reinterpret_cast<ushort*>(&bv);
}

// ---------------- agg: LDS counting sort (global-read) -> row-parallel register gather ---
__global__ __launch_bounds__(256) void agg_pool_mlp(
    const uint4* __restrict__ fnorm4, const int* __restrict__ gcursor,
    const unsigned* __restrict__ binned,
    const float* __restrict__ W, const float* __restrict__ b,
    const float* __restrict__ W2, const float* __restrict__ b2,
    const float* __restrict__ W3, const float* __restrict__ b3,
    float* __restrict__ out) {
    int blk = blockIdx.x;
    int t = threadIdx.x;
    int l = t & 3;
    int q = t >> 2;
    __shared__ unsigned sS[CAPE];
    __shared__ int cnt_n[128];
    __shared__ int start_n[128];
    __shared__ int cur_n[128];
    __shared__ int scan_s[128];
    __shared__ float sAcc[ROWS][33];
    __shared__ float sW[IN_F * H1];
    __shared__ float smax[8][32];
    __shared__ float pooled[32];
    __shared__ float z[H2];

    int cnt = gcursor[blk];
    if (cnt > CAPE) cnt = CAPE;
    const unsigned* bb = binned + (size_t)blk * CAPE;

    for (int i = t; i < 128; i += 256) cnt_n[i] = 0;
    for (int i = t; i < IN_F * H1; i += 256) sW[i] = W[i];
    __syncthreads();

    for (int i = t; i < cnt; i += 256) atomicAdd(&cnt_n[bb[i] & 127u], 1);
    __syncthreads();

    if (t < 128) scan_s[t] = cnt_n[t];
    __syncthreads();
    for (int o = 1; o < 128; o <<= 1) {
        int y = 0;
        if (t < 128 && t >= o) y = scan_s[t - o];
        __syncthreads();
        if (t < 128) scan_s[t] += y;
        __syncthreads();
    }
    if (t < 128) {
        int ex = scan_s[t] - cnt_n[t];
        start_n[t] = ex;
        cur_n[t] = ex;
    }
    __syncthreads();

    for (int i = t; i < cnt; i += 256) {
        unsigned e = bb[i];       // L2-hot second read
        int row = (int)(e & 127u);
        int pos = atomicAdd(&cur_n[row], 1);
        sS[pos] = e >> 7;
    }
    __syncthreads();

    for (int nn = q; nn < ROWS; nn += 64) {
        float a[8];
        #pragma unroll
        for (int j = 0; j < 8; j++) a[j] = 0.f;
        int st = start_n[nn];
        int dg = cnt_n[nn];
        for (int j = 0; j < dg; ++j) {
            unsigned id = sS[st + j];
            uint4 r = fnorm4[(size_t)id * 4 + l];
            const unsigned* w = reinterpret_cast<const unsigned*>(&r);
            #pragma unroll
            for (int k = 0; k < 4; k++) {
                a[2 * k]     += __uint_as_float(w[k] << 16);
                a[2 * k + 1] += __uint_as_float(w[k] & 0xffff0000u);
            }
        }
        #pragma unroll
        for (int j = 0; j < 8; j++) sAcc[nn][l * 8 + j] = a[j];
    }
    __syncthreads();

    int f = t & 31;
    int hw = t >> 5;
    #pragma unroll
    for (int gi = 0; gi < GPB; gi++) {
        float m = -INFINITY;
        for (int n = hw; n < NPG; n += 8) {
            int row = gi * NPG + n;
            float nd = rsqrtf(fmaxf((float)cnt_n[row], 1.0f));
            if (f < H1) {
                float s2 = 0.f;
                #pragma unroll
                for (int k = 0; k < IN_F; k++) s2 += sAcc[row][k] * sW[k * H1 + f];
                m = fmaxf(m, s2 * nd + b[f]);
            }
        }
        smax[hw][f] = m;
        __syncthreads();
        if (t < 32) {
            float mm = smax[0][t];
            #pragma unroll
            for (int k = 1; k < 8; k++) mm = fmaxf(mm, smax[k][t]);
            pooled[t] = mm;
        }
        __syncthreads();
        if (t < H2) {
            float s2 = b2[t];
            #pragma unroll
            for (int k = 0; k < H1; k++) s2 += pooled[k] * W2[k * H2 + t];
            z[t] = fmaxf(s2, 0.f);
        }
        __syncthreads();
        if (t < OUTF) {
            float s3 = b3[t];
            #pragma unroll
            for (int k = 0; k < H2; k++) s3 += z[k] * W3[k * OUTF + t];
            out[(GPB * blk + gi) * OUTF + t] = 1.f / (1.f + expf(-s3));
        }
        __syncthreads();
    }
}

extern "C" void kernel_launch(void* const* d_in, const int* in_sizes, int n_in,
                              void* d_out, int out_size, void* d_ws, size_t ws_size,
                              hipStream_t stream) {
    const float* feat = (const float*)d_in[0];
    const int*   src  = (const int*)d_in[1];
    const int*   dst  = (const int*)d_in[2];
    const float* W  = (const float*)d_in[5];
    const float* b  = (const float*)d_in[6];
    const float* W2 = (const float*)d_in[7];
    const float* b2 = (const float*)d_in[8];
    const float* W3 = (const float*)d_in[9];
    const float* b3 = (const float*)d_in[10];
    float* out = (float*)d_out;

    char* ws = (char*)d_ws;
    int* deg_out = (int*)ws;                           // 400000 (zeroed)
    int* gcursor = deg_out + N_NODES;                  // 5120   (zeroed)
    int* ccurD   = gcursor + 5120;                     // 1280   (zeroed)
    int* ccurS   = ccurD + 1280;                       // 1280   (zeroed)
    unsigned* coarseD = (unsigned*)(ccurS + 1280);     // 79*40960
    unsigned* coarseS = coarseD + (size_t)NC * CCAP;   // 79*40960
    unsigned* binned  = coarseS + (size_t)NC * CCAP;   // 5000*768
    ushort* fnorm = (ushort*)(binned + (size_t)PAIRS * CAPE);  // 25.6MB

    hipMemsetAsync(deg_out, 0, sizeof(int) * (N_NODES + 5120 + 1280 + 1280), stream);

    p1_split2<<<P1B, P1T, 0, stream>>>((const int4*)src, (const int4*)dst,
                                       ccurD, ccurS, coarseD, coarseS);
    p1_hist<<<NC * HPARTS, 256, 0, stream>>>(coarseS, ccurS, deg_out);

    p2_split<<<NC * P2BPB, P2T, 0, stream>>>(coarseD, ccurD, gcursor, binned);

    fnorm_kernel<<<(N_NODES * 32 + 255) / 256, 256, 0, stream>>>(feat, deg_out, fnorm);

    agg_pool_mlp<<<PAIRS, 256, 0, stream>>>((const uint4*)fnorm, gcursor, binned,
                                            W, b, W2, b2, W3, b3, out);
}

// Round 20
// 155.773 us; speedup vs baseline: 1.1974x; 1.0397x over previous
//
#include <hip/hip_runtime.h>
#include <hip/hip_bf16.h>
#include <math.h>

#define N_NODES 400000
#define N_EDGES 2400000
#define NPG 40
#define N_GRAPHS 10000
#define IN_F 30
#define H1 30
#define H2 10
#define OUTF 4
#define GPB 2
#define PAIRS (N_GRAPHS / GPB)      // 5000
#define ROWS (GPB * NPG)            // 80 dst rows per pair
#define CAPE 768                    // per-pair capacity (real ~480 + pads)
#define NC 79                       // coarse buckets
#define PPC 64                      // pairs per coarse bucket
#define NPC (PPC * ROWS)            // 5120 nodes per coarse bucket
#define SRC_PER_BUCK 5120
#define CCAP 40960                  // coarse capacity (real ~30.4k + pads ~5.1k)
#define P1B 640                     // blocks per role (~3752 edges each)
#define P1D 64                      // per-bucket LDS depth (mean fill 47.5)
#define P2BPB 8
#define P2GRID (NC * P2BPB)         // 632
#define HPARTS 8
#define HGRID (NC * HPARTS)         // 632
#define SENT 0xFFFFFFFFu

// ---------------- P1: role-split — dst-multisplit (role 0) / src-multisplit (role 1) ----
// One buf[NC][P1D] (21 KB) per block -> ~7 blocks/CU. Full-line drains as before.
__global__ __launch_bounds__(512) void p1_both(const int4* __restrict__ src4,
                                               const int4* __restrict__ dst4,
                                               int* __restrict__ ccurD,
                                               int* __restrict__ ccurS,
                                               unsigned* __restrict__ coarseD,
                                               unsigned* __restrict__ coarseS) {
    __shared__ unsigned buf[NC][P1D];
    __shared__ int cnt[NC], ftot[NC], fnf[NC], fbase[NC];
    int role = (blockIdx.x >= P1B) ? 1 : 0;
    int blk = blockIdx.x - role * P1B;
    int* __restrict__ ccur = role ? ccurS : ccurD;
    unsigned* __restrict__ coarse = role ? coarseS : coarseD;
    int t = threadIdx.x;
    for (int i = t; i < NC; i += 512) cnt[i] = 0;
    __syncthreads();
    const int n4 = N_EDGES / 4;
    const int per = (n4 + P1B - 1) / P1B;      // 938 int4s per block
    int lo = blk * per;
    int hi = lo + per; if (hi > n4) hi = n4;
    if (role == 0) {
        for (int i = lo + t; i < hi; i += 512) {
            int4 d = dst4[i];
            int4 s = src4[i];
            #pragma unroll
            for (int k = 0; k < 4; k++) {
                int dd = (k==0)?d.x:(k==1)?d.y:(k==2)?d.z:d.w;
                int ss = (k==0)?s.x:(k==1)?s.y:(k==2)?s.z:s.w;
                int bu = dd / NPC;
                int rem = dd - bu * NPC;
                int lp = rem / ROWS;
                int row = rem - lp * ROWS;
                unsigned e = ((unsigned)ss << 13) | ((unsigned)lp << 7) | (unsigned)row;
                int pos = atomicAdd(&cnt[bu], 1);
                if (pos < P1D) buf[bu][pos] = e;
                else {  // rare spill
                    int b2 = atomicAdd(&ccur[bu * 16], 1);
                    if (b2 < CCAP) coarse[bu * CCAP + b2] = e;
                }
            }
        }
    } else {
        for (int i = lo + t; i < hi; i += 512) {
            int4 s = src4[i];
            #pragma unroll
            for (int k = 0; k < 4; k++) {
                int ss = (k==0)?s.x:(k==1)?s.y:(k==2)?s.z:s.w;
                int bs = ss / SRC_PER_BUCK;
                int pos = atomicAdd(&cnt[bs], 1);
                if (pos < P1D) buf[bs][pos] = (unsigned)ss;
                else {
                    int b2 = atomicAdd(&ccur[bs * 16], 1);
                    if (b2 < CCAP) coarse[bs * CCAP + b2] = (unsigned)ss;
                }
            }
        }
    }
    __syncthreads();
    // single drain, sentinel-padded to full 16-entry lines
    if (t < NC) {
        int tot = min(cnt[t], P1D);
        int nf = (tot + 15) & ~15;
        ftot[t] = tot; fnf[t] = nf;
        fbase[t] = nf ? atomicAdd(&ccur[t * 16], nf) : 0;
    }
    __syncthreads();
    {
        int w = t >> 6, lane = t & 63;      // 8 waves
        for (int bu = w; bu < NC; bu += 8) {
            int nf = fnf[bu], base = fbase[bu], tot = ftot[bu];
            if (nf && base + nf <= CCAP)
                for (int j = lane; j < nf; j += 64)
                    coarse[bu * CCAP + base + j] = (j < tot) ? buf[bu][j] : SENT;
        }
    }
}

// ---------------- P2+HIST fused: role by blockIdx --------------------------------------
// role p2 (blocks < P2GRID): coarseD bucket -> per-pair binned segments (full-line).
// role hist (blocks >= P2GRID): coarseS bucket -> LDS histogram -> deg_out merge.
__global__ __launch_bounds__(512) void p2_hist(const unsigned* __restrict__ coarseD,
                                               const int* __restrict__ ccurD,
                                               const unsigned* __restrict__ coarseS,
                                               const int* __restrict__ ccurS,
                                               int* __restrict__ gcursor,
                                               unsigned* __restrict__ binned,
                                               int* __restrict__ deg_out) {
    __shared__ unsigned smem[8192];          // 32 KB union
    __shared__ int aux[PPC * 4];
    int t = threadIdx.x;
    if (blockIdx.x < P2GRID) {
        // ---- p2 role ----
        unsigned (*buf)[128] = (unsigned(*)[128])smem;
        int* cnt = aux; int* ftot = aux + PPC; int* fnf = aux + 2*PPC; int* fbase = aux + 3*PPC;
        int bu = blockIdx.x >> 3;
        int b2 = blockIdx.x & 7;
        for (int i = t; i < PPC; i += 512) cnt[i] = 0;
        __syncthreads();
        int total = min(ccurD[bu * 16], CCAP);
        int slice = (total + P2BPB - 1) / P2BPB;
        int lo = b2 * slice;
        int hi = min(lo + slice, total);
        const unsigned* cb = coarseD + (size_t)bu * CCAP;
        for (int idx = lo + t * 4; idx < hi; idx += 512 * 4) {
            uint4 r = *reinterpret_cast<const uint4*>(&cb[idx]);
            #pragma unroll
            for (int j = 0; j < 4; j++) {
                if (idx + j >= hi) break;
                unsigned e = (j==0)?r.x:(j==1)?r.y:(j==2)?r.z:r.w;
                if ((e >> 13) >= (unsigned)N_NODES) continue;   // sentinel
                int lp = (int)((e >> 7) & 63u);
                int pos = atomicAdd(&cnt[lp], 1);
                if (pos < 128) buf[lp][pos] = e;
                else {  // statistically never
                    int pr = bu * PPC + lp;
                    int pp = atomicAdd(&gcursor[pr], 1);
                    if (pp < CAPE) binned[pr * CAPE + pp] = ((e >> 13) << 7) | (e & 127u);
                }
            }
        }
        __syncthreads();
        if (t < PPC) {
            int tot = min(cnt[t], 128);
            int nf = (tot + 15) & ~15;
            ftot[t] = tot; fnf[t] = nf;
            fbase[t] = nf ? atomicAdd(&gcursor[bu * PPC + t], nf) : 0;
        }
        __syncthreads();
        {
            int w = t >> 6, lane = t & 63;      // 8 waves
            for (int lp = w; lp < PPC; lp += 8) {
                int nf = fnf[lp], base = fbase[lp], tot = ftot[lp];
                int pr = bu * PPC + lp;
                if (nf && base + nf <= CAPE)
                    for (int j = lane; j < nf; j += 64) {
                        unsigned v = (j < tot) ? (((buf[lp][j] >> 13) << 7) | (buf[lp][j] & 127u)) : SENT;
                        binned[pr * CAPE + base + j] = v;
                    }
            }
        }
    } else {
        // ---- hist role ----
        int* hist = (int*)smem;                  // 5120 ints = 20 KB of the union
        int hb = blockIdx.x - P2GRID;
        int bu = hb / HPARTS;
        int part = hb % HPARTS;
        for (int i = t; i < SRC_PER_BUCK; i += 512) hist[i] = 0;
        __syncthreads();
        int total = min(ccurS[bu * 16], CCAP);
        int slice = (total + HPARTS - 1) / HPARTS;
        int lo = part * slice;
        int hi = min(lo + slice, total);
        const unsigned* cb = coarseS + (size_t)bu * CCAP;
        int base = bu * SRC_PER_BUCK;
        for (int i = lo + t; i < hi; i += 512) {
            unsigned ssv = cb[i];
            if (ssv < (unsigned)N_NODES) atomicAdd(&hist[(int)ssv - base], 1);
        }
        __syncthreads();
        int lim = min(SRC_PER_BUCK, N_NODES - base);
        for (int i = t; i < lim; i += 512) {
            int v = hist[i];
            if (v) atomicAdd(&deg_out[base + i], v);
        }
    }
}

// ---------------- fnorm[n][f] = bf16(feat[n][f] * rsqrt(max(deg_out,1))), 32-padded ------
__global__ void fnorm_kernel(const float* __restrict__ feat, const int* __restrict__ deg_out,
                             ushort* __restrict__ fnorm) {
    int idx = blockIdx.x * blockDim.x + threadIdx.x;
    int n = idx >> 5;
    int f = idx & 31;
    if (n >= N_NODES) return;
    float ns = rsqrtf(fmaxf((float)deg_out[n], 1.0f));
    float v = (f < IN_F) ? feat[(size_t)n * IN_F + f] * ns : 0.f;
    __hip_bfloat16 bv = __float2bfloat16(v);
    fnorm[((size_t)n << 5) + f] = *reinterpret_cast<ushort*>(&bv);
}

// ---------------- agg: LDS counting sort (global-read) -> row-parallel register gather ---
__global__ __launch_bounds__(256) void agg_pool_mlp(
    const uint4* __restrict__ fnorm4, const int* __restrict__ gcursor,
    const unsigned* __restrict__ binned,
    const float* __restrict__ W, const float* __restrict__ b,
    const float* __restrict__ W2, const float* __restrict__ b2,
    const float* __restrict__ W3, const float* __restrict__ b3,
    float* __restrict__ out) {
    int blk = blockIdx.x;
    int t = threadIdx.x;
    int l = t & 3;
    int q = t >> 2;
    __shared__ unsigned sS[CAPE];
    __shared__ int cnt_n[128];
    __shared__ int start_n[128];
    __shared__ int cur_n[128];
    __shared__ int scan_s[128];
    __shared__ float sAcc[ROWS][33];
    __shared__ float sW[IN_F * H1];
    __shared__ float smax[8][32];
    __shared__ float pooled[32];
    __shared__ float z[H2];

    int cnt = gcursor[blk];
    if (cnt > CAPE) cnt = CAPE;
    const unsigned* bb = binned + (size_t)blk * CAPE;

    for (int i = t; i < 128; i += 256) cnt_n[i] = 0;
    for (int i = t; i < IN_F * H1; i += 256) sW[i] = W[i];
    __syncthreads();

    for (int i = t; i < cnt; i += 256) atomicAdd(&cnt_n[bb[i] & 127u], 1);
    __syncthreads();

    if (t < 128) scan_s[t] = cnt_n[t];
    __syncthreads();
    for (int o = 1; o < 128; o <<= 1) {
        int y = 0;
        if (t < 128 && t >= o) y = scan_s[t - o];
        __syncthreads();
        if (t < 128) scan_s[t] += y;
        __syncthreads();
    }
    if (t < 128) {
        int ex = scan_s[t] - cnt_n[t];
        start_n[t] = ex;
        cur_n[t] = ex;
    }
    __syncthreads();

    for (int i = t; i < cnt; i += 256) {
        unsigned e = bb[i];       // L2-hot second read
        int row = (int)(e & 127u);
        int pos = atomicAdd(&cur_n[row], 1);
        sS[pos] = e >> 7;
    }
    __syncthreads();

    for (int nn = q; nn < ROWS; nn += 64) {
        float a[8];
        #pragma unroll
        for (int j = 0; j < 8; j++) a[j] = 0.f;
        int st = start_n[nn];
        int dg = cnt_n[nn];
        for (int j = 0; j < dg; ++j) {
            unsigned id = sS[st + j];
            uint4 r = fnorm4[(size_t)id * 4 + l];
            const unsigned* w = reinterpret_cast<const unsigned*>(&r);
            #pragma unroll
            for (int k = 0; k < 4; k++) {
                a[2 * k]     += __uint_as_float(w[k] << 16);
                a[2 * k + 1] += __uint_as_float(w[k] & 0xffff0000u);
            }
        }
        #pragma unroll
        for (int j = 0; j < 8; j++) sAcc[nn][l * 8 + j] = a[j];
    }
    __syncthreads();

    int f = t & 31;
    int hw = t >> 5;
    #pragma unroll
    for (int gi = 0; gi < GPB; gi++) {
        float m = -INFINITY;
        for (int n = hw; n < NPG; n += 8) {
            int row = gi * NPG + n;
            float nd = rsqrtf(fmaxf((float)cnt_n[row], 1.0f));
            if (f < H1) {
                float s2 = 0.f;
                #pragma unroll
                for (int k = 0; k < IN_F; k++) s2 += sAcc[row][k] * sW[k * H1 + f];
                m = fmaxf(m, s2 * nd + b[f]);
            }
        }
        smax[hw][f] = m;
        __syncthreads();
        if (t < 32) {
            float mm = smax[0][t];
            #pragma unroll
            for (int k = 1; k < 8; k++) mm = fmaxf(mm, smax[k][t]);
            pooled[t] = mm;
        }
        __syncthreads();
        if (t < H2) {
            float s2 = b2[t];
            #pragma unroll
            for (int k = 0; k < H1; k++) s2 += pooled[k] * W2[k * H2 + t];
            z[t] = fmaxf(s2, 0.f);
        }
        __syncthreads();
        if (t < OUTF) {
            float s3 = b3[t];
            #pragma unroll
            for (int k = 0; k < H2; k++) s3 += z[k] * W3[k * OUTF + t];
            out[(GPB * blk + gi) * OUTF + t] = 1.f / (1.f + expf(-s3));
        }
        __syncthreads();
    }
}

extern "C" void kernel_launch(void* const* d_in, const int* in_sizes, int n_in,
                              void* d_out, int out_size, void* d_ws, size_t ws_size,
                              hipStream_t stream) {
    const float* feat = (const float*)d_in[0];
    const int*   src  = (const int*)d_in[1];
    const int*   dst  = (const int*)d_in[2];
    const float* W  = (const float*)d_in[5];
    const float* b  = (const float*)d_in[6];
    const float* W2 = (const float*)d_in[7];
    const float* b2 = (const float*)d_in[8];
    const float* W3 = (const float*)d_in[9];
    const float* b3 = (const float*)d_in[10];
    float* out = (float*)d_out;

    char* ws = (char*)d_ws;
    int* deg_out = (int*)ws;                           // 400000 (zeroed)
    int* gcursor = deg_out + N_NODES;                  // 5120   (zeroed)
    int* ccurD   = gcursor + 5120;                     // 1280   (zeroed)
    int* ccurS   = ccurD + 1280;                       // 1280   (zeroed)
    unsigned* coarseD = (unsigned*)(ccurS + 1280);     // 79*40960
    unsigned* coarseS = coarseD + (size_t)NC * CCAP;   // 79*40960
    unsigned* binned  = coarseS + (size_t)NC * CCAP;   // 5000*768
    ushort* fnorm = (ushort*)(binned + (size_t)PAIRS * CAPE);  // 25.6MB

    hipMemsetAsync(deg_out, 0, sizeof(int) * (N_NODES + 5120 + 1280 + 1280), stream);

    p1_both<<<2 * P1B, 512, 0, stream>>>((const int4*)src, (const int4*)dst,
                                         ccurD, ccurS, coarseD, coarseS);

    p2_hist<<<P2GRID + HGRID, 512, 0, stream>>>(coarseD, ccurD, coarseS, ccurS,
                                                gcursor, binned, deg_out);

    fnorm_kernel<<<(N_NODES * 32 + 255) / 256, 256, 0, stream>>>(feat, deg_out, fnorm);

    agg_pool_mlp<<<PAIRS, 256, 0, stream>>>((const uint4*)fnorm, gcursor, binned,
                                            W, b, W2, b2, W3, b3, out);
}